// Round 13
// baseline (539.149 us; speedup 1.0000x reference)
//
#include <hip/hip_runtime.h>
#include <hip/hip_bf16.h>

constexpr int SEQ = 2048;
constexpr int EMB = 4096;
constexpr int NH  = 32;
constexpr int HD  = 128;
constexpr int HALF = 64;

typedef __bf16 bf16x8 __attribute__((ext_vector_type(8)));
typedef float  f32x4  __attribute__((ext_vector_type(4)));
using u16 = unsigned short;
typedef u16 ushort8 __attribute__((ext_vector_type(8)));
typedef u16 u16x4 __attribute__((ext_vector_type(4)));

__device__ inline float bf2f(u16 u) {
  union { unsigned int i; float f; } v; v.i = ((unsigned int)u) << 16; return v.f;
}
__device__ inline u16 f2bf(float f) {
  union { __bf16 b; u16 u; } v; v.b = (__bf16)f; return v.u;
}

#define GLL16(gp, lp) __builtin_amdgcn_global_load_lds( \
    (const __attribute__((address_space(1))) void*)(gp), \
    (__attribute__((address_space(3))) void*)(lp), 16, 0, 0)

// ---------------- fp32 -> bf16 conversion (vectorized) ----------------
__global__ void k_f32_to_bf16(const float* __restrict__ in, u16* __restrict__ out, int n) {
  int i = (blockIdx.x * blockDim.x + threadIdx.x) * 8;
  if (i >= n) return;
  f32x4 a = *(const f32x4*)(in + i);
  f32x4 b = *(const f32x4*)(in + i + 4);
  ushort8 o;
  o[0] = f2bf(a[0]); o[1] = f2bf(a[1]); o[2] = f2bf(a[2]); o[3] = f2bf(a[3]);
  o[4] = f2bf(b[0]); o[5] = f2bf(b[1]); o[6] = f2bf(b[2]); o[7] = f2bf(b[3]);
  *(ushort8*)(out + i) = o;
}

// 3 weight matrices (each EMB*EMB = 2^24 elems) -> contiguous bf16 buffer
__global__ void k_w3_to_bf16(const float* __restrict__ w0, const float* __restrict__ w1,
                             const float* __restrict__ w2, u16* __restrict__ out) {
  size_t i = ((size_t)blockIdx.x * blockDim.x + threadIdx.x) * 8;
  int seg = (int)(i >> 24);
  size_t off = i & ((1u << 24) - 1);
  const float* src = (seg == 0) ? w0 : (seg == 1) ? w1 : w2;
  f32x4 a = *(const f32x4*)(src + off);
  f32x4 b = *(const f32x4*)(src + off + 4);
  ushort8 o;
  o[0] = f2bf(a[0]); o[1] = f2bf(a[1]); o[2] = f2bf(a[2]); o[3] = f2bf(a[3]);
  o[4] = f2bf(b[0]); o[5] = f2bf(b[1]); o[6] = f2bf(b[2]); o[7] = f2bf(b[3]);
  *(ushort8*)(out + i) = o;
}

// ---------------- RoPE cos/sin table (fp64 for exactness) ----------------
__global__ void k_rope_table(const int* __restrict__ pos, float* __restrict__ tab) {
  int idx = blockIdx.x * blockDim.x + threadIdx.x;
  if (idx >= SEQ * HALF) return;
  int s = idx >> 6, d = idx & 63;
  double invf = pow(10000.0, -(double)d / 64.0);
  double ang = (double)pos[s] * invf;
  tab[idx * 2]     = (float)cos(ang);
  tab[idx * 2 + 1] = (float)sin(ang);
}

// ---------------- RoPE apply (in-place on bf16, optional 1/sqrt(D) fold) ----------------
__global__ void k_rope(u16* __restrict__ X, const float* __restrict__ tab, float scale) {
  int idx = blockIdx.x * blockDim.x + threadIdx.x;   // SEQ*NH*HALF
  if (idx >= SEQ * NH * HALF) return;
  int d = idx & 63;
  int h = (idx >> 6) & 31;
  int s = idx >> 11;
  u16* p = X + (size_t)s * EMB + h * HD + d;
  float x1 = bf2f(p[0]), x2 = bf2f(p[HALF]);
  float c  = tab[(s * HALF + d) * 2];
  float sn = tab[(s * HALF + d) * 2 + 1];
  p[0]    = f2bf((x1 * c - x2 * sn) * scale);
  p[HALF] = f2bf((x2 * c + x1 * sn) * scale);
}

// ======== GEMM, BK=64: TBMx256 tile, 2 LDS buffers, 1 barrier per 64-K ========
// C = A[M][K] * W[N][K]^T + bias. 8 waves (2Mx4N), per-wave (TBM/2)x64, acc 128 VGPR.
// Per K-tile t: { vmcnt(0): tile-t stage (issued a full tile ago) arrived;
//   s_barrier: collective; burst-stage tile t+1 into other buffer (8 gload_lds);
//   24 ds_read_b128 + 64 MFMA in 4 setprio'd clusters, compiler-scheduled }.
// Write-safe: buf (t+1)&1's reads were consumed by MFMAs before tile t's barrier.
// Read-safe: vmcnt(0) covers exactly tile t's loads; lead = 1 full tile (~600cy)
// covers the mostly-L2-hit staging latency.
// Swizzle: LDS dest linear (idx*16B); global source supplies k-unit (pb-row)&7;
// reads use ((ks*4+lhi)+row)&7 — all 32 banks covered, 2-way = free.
// mode: 0 bf16 [M][N], 1 f32 [M][N], 2 bf16 V^T [n][M],
//       3 QKV fused (N=12288; seg n0>>12: 0->C0, 1->C1, 2->C2 V^T)
template<int TBM>
__global__ __launch_bounds__(512, 1) void k_gemm64(
    const u16* __restrict__ Ag, const u16* __restrict__ Wg,
    const float* __restrict__ b0, const float* __restrict__ b1, const float* __restrict__ b2,
    void* __restrict__ C0, void* __restrict__ C1, void* __restrict__ C2,
    int M, int N, int K, int mode)
{
  constexpr int MA = TBM / 32;          // A frags per wave (8 or 4)
  constexpr int MH = MA / 4;            // M-half phases (2 or 1)
  constexpr int LA = TBM / 64;          // stageA loads per thread (4 or 2)
  __shared__ alignas(16) u16 As[2][TBM * 64];
  __shared__ alignas(16) u16 Bs[2][256 * 64];

  int tid = threadIdx.x;
  int lane = tid & 63, wid = tid >> 6;
  int wm = wid >> 2, wn = wid & 3;      // 2 x 4 waves
  int l15 = lane & 15, lhi = lane >> 4;

  // XCD-compact bijective mapping (grid % 8 == 0; NBX % 8 == 0)
  int NBY = M / TBM, NBX = N >> 8;
  int wg = blockIdx.x;
  int xcd = wg & 7, sgl = wg >> 3;
  int by = sgl % NBY, bxl = sgl / NBY;
  int bx = xcd * (NBX >> 3) + bxl;
  int m0 = by * TBM, n0 = bx * 256;

  auto stage = [&](int b, int k0) {
#pragma unroll
    for (int ld = 0; ld < LA; ld++) {
      int idx = ld * 512 + tid;               // < TBM*8
      int row = idx >> 3, pb = idx & 7;
      int kb = (pb - row) & 7;
      GLL16(Ag + (size_t)(m0 + row) * K + k0 + kb * 8, &As[b][idx * 8]);
    }
#pragma unroll
    for (int ld = 0; ld < 4; ld++) {
      int idx = ld * 512 + tid;               // < 2048
      int row = idx >> 3, pb = idx & 7;
      int kb = (pb - row) & 7;
      GLL16(Wg + (size_t)(n0 + row) * K + k0 + kb * 8, &Bs[b][idx * 8]);
    }
  };

  f32x4 acc[MA][4] = {};
  int KT = K >> 6;

  stage(0, 0);
  for (int t = 0; t < KT; t++) {
    asm volatile("s_waitcnt vmcnt(0)" ::: "memory");
    __builtin_amdgcn_s_barrier();
    __builtin_amdgcn_sched_barrier(0);
    if (t + 1 < KT) {
      stage((t + 1) & 1, (t + 1) << 6);
      __builtin_amdgcn_sched_barrier(0);      // pin stages early (max lead)
    }

    const u16* as = &As[t & 1][0];
    const u16* bs = &Bs[t & 1][0];
#pragma unroll
    for (int ks = 0; ks < 2; ks++) {
      bf16x8 bfr[4];
#pragma unroll
      for (int q = 0; q < 4; q++) {
        int row = wn * 64 + q * 16 + l15;
        bfr[q] = *(const bf16x8*)&bs[row * 64 + (((ks * 4 + lhi) + row) & 7) * 8];
      }
#pragma unroll
      for (int mh = 0; mh < MH; mh++) {
        bf16x8 af[4];
#pragma unroll
        for (int p = 0; p < 4; p++) {
          int row = wm * (TBM / 2) + mh * 64 + p * 16 + l15;
          af[p] = *(const bf16x8*)&as[row * 64 + (((ks * 4 + lhi) + row) & 7) * 8];
        }
        __builtin_amdgcn_s_setprio(1);
#pragma unroll
        for (int p = 0; p < 4; p++)
#pragma unroll
          for (int q = 0; q < 4; q++)
            acc[mh * 4 + p][q] =
                __builtin_amdgcn_mfma_f32_16x16x32_bf16(af[p], bfr[q], acc[mh * 4 + p][q], 0, 0, 0);
        __builtin_amdgcn_s_setprio(0);
      }
    }
  }

  // epilogue: resolve output segment
  int mode_l = mode, Nn = N, n_base = n0;
  const float* bias = b0;
  void* Cout = C0;
  if (mode == 3) {
    int seg = n0 >> 12;
    Nn = EMB; n_base = n0 & 4095;
    if (seg == 0)      { bias = b0; Cout = C0; mode_l = 0; }
    else if (seg == 1) { bias = b1; Cout = C1; mode_l = 0; }
    else               { bias = b2; Cout = C2; mode_l = 2; }
  }

#pragma unroll
  for (int p = 0; p < MA; p++) {
    int m = m0 + wm * (TBM / 2) + p * 16 + lhi * 4;
#pragma unroll
    for (int q = 0; q < 4; q++) {
      int n = n_base + wn * 64 + q * 16 + l15;
      float bs2 = bias[n];
      if (mode_l == 2) {
        u16x4 pk;
#pragma unroll
        for (int r = 0; r < 4; r++) pk[r] = f2bf(acc[p][q][r] + bs2);
        *(u16x4*)&((u16*)Cout)[(size_t)n * M + m] = pk;   // V^T
      } else if (mode_l == 1) {
#pragma unroll
        for (int r = 0; r < 4; r++)
          ((float*)Cout)[(size_t)(m + r) * Nn + n] = acc[p][q][r] + bs2;
      } else {
#pragma unroll
        for (int r = 0; r < 4; r++)
          ((u16*)Cout)[(size_t)(m + r) * Nn + n] = f2bf(acc[p][q][r] + bs2);
      }
    }
  }
}

// ---------------- Flash attention (causal), QB=128 (8 waves x 16 rows), KVB=64 ----------
constexpr int QB = 128, KVB = 64;

__global__ __launch_bounds__(512) void k_flash(
    const u16* __restrict__ Q, const u16* __restrict__ K, const u16* __restrict__ VT,
    u16* __restrict__ ctx)
{
  __shared__ alignas(16) u16 Ks[2][KVB * 128];
  __shared__ alignas(16) u16 Vt[2][HD * 64];
  __shared__ alignas(16) u16 Pl[8][16 * 64];

  int tid = threadIdx.x, lane = tid & 63, wid = tid >> 6;   // wid 0..7
  int l15 = lane & 15, lhi = lane >> 4;
  int h = blockIdx.y;

  auto stage = [&](int buf, int t2) {
    int kv = t2 * KVB;
#pragma unroll
    for (int it = 0; it < 2; it++) {
      int chunk = tid + it * 512;          // 0..1023
      int r = chunk >> 4, bp = chunk & 15;
      GLL16(K + (size_t)(kv + r) * EMB + h * HD + (((bp - r) & 15) << 3), &Ks[buf][chunk * 8]);
    }
#pragma unroll
    for (int it = 0; it < 2; it++) {
      int chunk = tid + it * 512;
      int d = chunk >> 3, bp = chunk & 7;
      GLL16(VT + (size_t)(h * HD + d) * SEQ + kv + (((bp - d) & 7) << 3), &Vt[buf][chunk * 8]);
    }
  };

  for (int pi = 0; pi < 2; pi++) {
    int qb = pi ? (int)blockIdx.x : 15 - (int)blockIdx.x;   // heavy first
    int q0 = qb * QB;
    int qw = q0 + wid * 16;

    bf16x8 qf[4];
#pragma unroll
    for (int kc = 0; kc < 4; kc++)
      qf[kc] = *(const bf16x8*)&Q[(size_t)(qw + l15) * EMB + h * HD + kc * 32 + lhi * 8];

    f32x4 O[8] = {};
    float mrow[4], lrow[4];
#pragma unroll
    for (int r = 0; r < 4; r++) { mrow[r] = -3.0e38f; lrow[r] = 0.f; }

    int nt = 2 * (qb + 1);
    __syncthreads();
    stage(0, 0);
    for (int t = 0; t < nt; t++) {
      __syncthreads();
      if (t + 1 < nt) stage((t + 1) & 1, t + 1);

      int kv0 = t * KVB;
      if (kv0 > qw + 15) continue;   // fully masked for this wave

      const u16* ks = Ks[t & 1];
      const u16* vt = Vt[t & 1];
      float p[4][4];
      bool need_mask = (kv0 + KVB - 1) > qw;
#pragma unroll
      for (int c = 0; c < 4; c++) {
        f32x4 s = {};
        int r0 = c * 16 + l15;
#pragma unroll
        for (int kc = 0; kc < 4; kc++) {
          bf16x8 kf = *(const bf16x8*)&ks[r0 * 128 + (((kc * 4 + lhi) + r0) & 15) * 8];
          s = __builtin_amdgcn_mfma_f32_16x16x32_bf16(qf[kc], kf, s, 0, 0, 0);
        }
#pragma unroll
        for (int r = 0; r < 4; r++) {
          float sv = s[r];
          if (need_mask) {
            int qg = qw + lhi * 4 + r;
            int kg = kv0 + c * 16 + l15;
            if (kg > qg) sv = -3.0e38f;
          }
          p[c][r] = sv;
        }
      }
      float fscale[4];
#pragma unroll
      for (int r = 0; r < 4; r++) {
        float m = fmaxf(fmaxf(p[0][r], p[1][r]), fmaxf(p[2][r], p[3][r]));
#pragma unroll
        for (int x = 1; x < 16; x <<= 1) m = fmaxf(m, __shfl_xor(m, x, 64));
        float mnew = fmaxf(mrow[r], m);
        fscale[r] = __expf(mrow[r] - mnew);
        mrow[r] = mnew;
      }
#pragma unroll
      for (int c = 0; c < 4; c++)
#pragma unroll
        for (int r = 0; r < 4; r++)
          p[c][r] = __expf(p[c][r] - mrow[r]);
#pragma unroll
      for (int r = 0; r < 4; r++) {
        float s = p[0][r] + p[1][r] + p[2][r] + p[3][r];
#pragma unroll
        for (int x = 1; x < 16; x <<= 1) s += __shfl_xor(s, x, 64);
        lrow[r] = lrow[r] * fscale[r] + s;
      }
#pragma unroll
      for (int d = 0; d < 8; d++)
#pragma unroll
        for (int r = 0; r < 4; r++)
          O[d][r] *= fscale[r];
#pragma unroll
      for (int c = 0; c < 4; c++) {
        int kb = c * 2 + (l15 >> 3), klo = l15 & 7;
#pragma unroll
        for (int r = 0; r < 4; r++) {
          int q = lhi * 4 + r;
          Pl[wid][q * 64 + ((kb + (q >> 1)) & 7) * 8 + klo] = f2bf(p[c][r]);
        }
      }
#pragma unroll
      for (int ks2 = 0; ks2 < 2; ks2++) {
        int kb = ks2 * 4 + lhi;
        bf16x8 pf = *(const bf16x8*)&Pl[wid][l15 * 64 + ((kb + (l15 >> 1)) & 7) * 8];
#pragma unroll
        for (int ds = 0; ds < 8; ds++) {
          int d = ds * 16 + l15;
          bf16x8 vf = *(const bf16x8*)&vt[d * 64 + ((kb + d) & 7) * 8];
          O[ds] = __builtin_amdgcn_mfma_f32_16x16x32_bf16(pf, vf, O[ds], 0, 0, 0);
        }
      }
    }

#pragma unroll
    for (int r = 0; r < 4; r++) {
      float inv = 1.f / lrow[r];
      int qg = q0 + wid * 16 + lhi * 4 + r;
#pragma unroll
      for (int ds = 0; ds < 8; ds++)
        ctx[(size_t)qg * EMB + h * HD + ds * 16 + l15] = f2bf(O[ds][r] * inv);
    }
  }
}

// ---------------- launch ----------------
extern "C" void kernel_launch(void* const* d_in, const int* in_sizes, int n_in,
                              void* d_out, int out_size, void* d_ws, size_t ws_size,
                              hipStream_t stream) {
  const float* hs = (const float*)d_in[0];
  const float* wq = (const float*)d_in[1];
  const float* bq = (const float*)d_in[2];
  const float* wk = (const float*)d_in[3];
  const float* bk = (const float*)d_in[4];
  const float* wv = (const float*)d_in[5];
  const float* bv = (const float*)d_in[6];
  const float* wo = (const float*)d_in[7];
  const float* bo = (const float*)d_in[8];
  const int*  pos = (const int*)d_in[9];

  const size_t SE = (size_t)SEQ * EMB;   // 8M elems
  const size_t EE = (size_t)EMB * EMB;   // 16M elems = 2^24
  const float qscale = 1.0f / 11.313708498984761f;  // 1/sqrt(128)

  char* ws = (char*)d_ws;
  size_t off = 0;
  auto alloc = [&](size_t b) { size_t o = off; off += (b + 255) & ~(size_t)255; return o; };

  size_t need_fused = ((SE * 2 + 255) & ~255ULL) + ((EE * 6 + 255) & ~255ULL) +
                      3 * ((SE * 2 + 255) & ~255ULL) + ((size_t)SEQ * HALF * 8 + 255);
  bool fused = ws_size >= need_fused + 4096;

  u16*  hsb = (u16*)(ws + alloc(SE * 2));
  u16*  wb  = (u16*)(ws + alloc(fused ? EE * 6 : EE * 2));  // fused: wq|wk|wv, reused for wo
  u16*  Qb  = (u16*)(ws + alloc(SE * 2));
  u16*  Kb  = (u16*)(ws + alloc(SE * 2));
  u16*  VTb = (u16*)(ws + alloc(SE * 2));                   // V^T, [E][S]
  float* tab = (float*)(ws + alloc((size_t)SEQ * HALF * 2 * 4));
  u16*  ctxb = hsb;   // hs dead after QKV GEMM; flash output reuses it

  dim3 cb(256);
  k_f32_to_bf16<<<dim3(SE / 2048), cb, 0, stream>>>(hs, hsb, (int)SE);
  k_rope_table<<<dim3(SEQ * HALF / 256), cb, 0, stream>>>(pos, tab);

  if (fused) {
    k_w3_to_bf16<<<dim3(3 * EE / 2048), cb, 0, stream>>>(wq, wk, wv, wb);
    // fused QKV GEMM: 256x256 tile, BK=64, grid 384
    k_gemm64<256><<<dim3(384), dim3(512), 0, stream>>>(
        hsb, wb, bq, bk, bv, (void*)Qb, (void*)Kb, (void*)VTb, SEQ, 3 * EMB, EMB, 3);
  } else {
    k_f32_to_bf16<<<dim3(EE / 2048), cb, 0, stream>>>(wq, wb, (int)EE);
    k_gemm64<128><<<dim3(256), dim3(512), 0, stream>>>(
        hsb, wb, bq, bq, bq, (void*)Qb, nullptr, nullptr, SEQ, EMB, EMB, 0);
    k_f32_to_bf16<<<dim3(EE / 2048), cb, 0, stream>>>(wk, wb, (int)EE);
    k_gemm64<128><<<dim3(256), dim3(512), 0, stream>>>(
        hsb, wb, bk, bk, bk, (void*)Kb, nullptr, nullptr, SEQ, EMB, EMB, 0);
    k_f32_to_bf16<<<dim3(EE / 2048), cb, 0, stream>>>(wv, wb, (int)EE);
    k_gemm64<128><<<dim3(256), dim3(512), 0, stream>>>(
        hsb, wb, bv, bv, bv, (void*)VTb, nullptr, nullptr, SEQ, EMB, EMB, 2);
  }

  k_rope<<<dim3(SEQ * NH * HALF / 256), cb, 0, stream>>>(Qb, tab, qscale);
  k_rope<<<dim3(SEQ * NH * HALF / 256), cb, 0, stream>>>(Kb, tab, 1.0f);

  // attention: QB=128, grid 8x32 = 256 blocks
  k_flash<<<dim3(8, NH), dim3(512), 0, stream>>>(Qb, Kb, VTb, ctxb);

  // output projection: 128x256 tile, BK=64 -> grid 256, f32 out
  k_f32_to_bf16<<<dim3(EE / 2048), cb, 0, stream>>>(wo, wb, (int)EE);
  k_gemm64<128><<<dim3(256), dim3(512), 0, stream>>>(
      ctxb, wb, bo, bo, bo, d_out, nullptr, nullptr, SEQ, EMB, EMB, 1);
}

// Round 14
// 483.621 us; speedup vs baseline: 1.1148x; 1.1148x over previous
//
#include <hip/hip_runtime.h>
#include <hip/hip_bf16.h>

constexpr int SEQ = 2048;
constexpr int EMB = 4096;
constexpr int NH  = 32;
constexpr int HD  = 128;
constexpr int HALF = 64;

typedef __bf16 bf16x8 __attribute__((ext_vector_type(8)));
typedef float  f32x4  __attribute__((ext_vector_type(4)));
using u16 = unsigned short;
typedef u16 ushort8 __attribute__((ext_vector_type(8)));
typedef u16 u16x4 __attribute__((ext_vector_type(4)));

__device__ inline float bf2f(u16 u) {
  union { unsigned int i; float f; } v; v.i = ((unsigned int)u) << 16; return v.f;
}
__device__ inline u16 f2bf(float f) {
  union { __bf16 b; u16 u; } v; v.b = (__bf16)f; return v.u;
}

#define GLL16(gp, lp) __builtin_amdgcn_global_load_lds( \
    (const __attribute__((address_space(1))) void*)(gp), \
    (__attribute__((address_space(3))) void*)(lp), 16, 0, 0)

// ---------------- fp32 -> bf16 conversion (vectorized) ----------------
__global__ void k_f32_to_bf16(const float* __restrict__ in, u16* __restrict__ out, int n) {
  int i = (blockIdx.x * blockDim.x + threadIdx.x) * 8;
  if (i >= n) return;
  f32x4 a = *(const f32x4*)(in + i);
  f32x4 b = *(const f32x4*)(in + i + 4);
  ushort8 o;
  o[0] = f2bf(a[0]); o[1] = f2bf(a[1]); o[2] = f2bf(a[2]); o[3] = f2bf(a[3]);
  o[4] = f2bf(b[0]); o[5] = f2bf(b[1]); o[6] = f2bf(b[2]); o[7] = f2bf(b[3]);
  *(ushort8*)(out + i) = o;
}

// 3 weight matrices (each EMB*EMB = 2^24 elems) -> contiguous bf16 buffer
__global__ void k_w3_to_bf16(const float* __restrict__ w0, const float* __restrict__ w1,
                             const float* __restrict__ w2, u16* __restrict__ out) {
  size_t i = ((size_t)blockIdx.x * blockDim.x + threadIdx.x) * 8;
  int seg = (int)(i >> 24);
  size_t off = i & ((1u << 24) - 1);
  const float* src = (seg == 0) ? w0 : (seg == 1) ? w1 : w2;
  f32x4 a = *(const f32x4*)(src + off);
  f32x4 b = *(const f32x4*)(src + off + 4);
  ushort8 o;
  o[0] = f2bf(a[0]); o[1] = f2bf(a[1]); o[2] = f2bf(a[2]); o[3] = f2bf(a[3]);
  o[4] = f2bf(b[0]); o[5] = f2bf(b[1]); o[6] = f2bf(b[2]); o[7] = f2bf(b[3]);
  *(ushort8*)(out + i) = o;
}

// ---------------- RoPE cos/sin table (fp64 for exactness) ----------------
__global__ void k_rope_table(const int* __restrict__ pos, float* __restrict__ tab) {
  int idx = blockIdx.x * blockDim.x + threadIdx.x;
  if (idx >= SEQ * HALF) return;
  int s = idx >> 6, d = idx & 63;
  double invf = pow(10000.0, -(double)d / 64.0);
  double ang = (double)pos[s] * invf;
  tab[idx * 2]     = (float)cos(ang);
  tab[idx * 2 + 1] = (float)sin(ang);
}

// ---------------- RoPE apply (in-place on bf16, optional 1/sqrt(D) fold) ----------------
__global__ void k_rope(u16* __restrict__ X, const float* __restrict__ tab, float scale) {
  int idx = blockIdx.x * blockDim.x + threadIdx.x;   // SEQ*NH*HALF
  if (idx >= SEQ * NH * HALF) return;
  int d = idx & 63;
  int h = (idx >> 6) & 31;
  int s = idx >> 11;
  u16* p = X + (size_t)s * EMB + h * HD + d;
  float x1 = bf2f(p[0]), x2 = bf2f(p[HALF]);
  float c  = tab[(s * HALF + d) * 2];
  float sn = tab[(s * HALF + d) * 2 + 1];
  p[0]    = f2bf((x1 * c - x2 * sn) * scale);
  p[HALF] = f2bf((x2 * c + x1 * sn) * scale);
}

// ======== GEMM (r8 structure): TBMxTBN tile, BK=32, 4 LDS buffers, 3-ahead ========
// C = A[M][K] * W[N][K]^T + bias. 8 waves (2Mx4N), per-wave (TBM/2)x(TBN/4).
// Tile t reads buf[t&3]; tile t+3 staged during tile t's MFMA phases (race-free:
// that buf's reads were consumed before tile t's top barrier; stage issues after).
// Counted vmcnt: steady 2*LPT, tail LPT, then 0. TBN=192 -> B stage is 1.5
// loads/thread: waves 0-3 take the extra half (wave-uniform), so vmcnt constants
// differ per wave group (8/6, 4/3).
// Epilogue resolves the QKV segment PER COLUMN (a 192-wide tile may cross the
// 4096 boundary). mode: 0 bf16 [M][N], 1 f32 [M][N], 2 bf16 V^T [n][M], 3 QKV.
template<int TBM, int TBN>
__global__ __launch_bounds__(512, 1) void k_qkv4(
    const u16* __restrict__ Ag, const u16* __restrict__ Wg,
    const float* __restrict__ b0, const float* __restrict__ b1, const float* __restrict__ b2,
    void* __restrict__ C0, void* __restrict__ C1, void* __restrict__ C2,
    int M, int N, int K, int mode)
{
  constexpr int LDA = TBM / 128;            // stageA loads per thread (2 or 1)
  constexpr int MA  = TBM / 32;             // A frags per wave (8 or 4)
  constexpr int NB  = TBN / 64;             // B frags per wave (4 or 3)
  constexpr int WNC = TBN / 4;              // cols per wave (64 or 48)
  __shared__ alignas(16) u16 As[4][TBM * 32];
  __shared__ alignas(16) u16 Bs[4][TBN * 32];

  int tid = threadIdx.x;
  int lane = tid & 63, wid = tid >> 6;
  int wm = wid >> 2, wn = wid & 3;          // 2 x 4 waves
  int l15 = lane & 15, lhi = lane >> 4;

  // XCD-compact bijective mapping (grid % 8 == 0; NBX % 8 == 0 or NBX>>3 >= 1 exact)
  int NBY = M / TBM, NBX = N / TBN;
  int wg = blockIdx.x;
  int xcd = wg & 7, sgl = wg >> 3;
  int by = sgl % NBY, bxl = sgl / NBY;
  int bx = xcd * (NBX >> 3) + bxl;
  int m0 = by * TBM, n0 = bx * TBN;

  auto stageA = [&](int b, int k0) {
#pragma unroll
    for (int ld = 0; ld < LDA; ld++) {
      int idx = ld * 512 + tid;
      int row = idx >> 2, pb = idx & 3;
      int kb = (pb - row - (row >> 2)) & 3;
      GLL16(Ag + (size_t)(m0 + row) * K + k0 + kb * 8, &As[b][idx * 8]);
    }
  };
  auto stageB = [&](int b, int k0) {
    {
      int idx = tid;                        // units 0..511
      int row = idx >> 2, pb = idx & 3;
      int kb = (pb - row - (row >> 2)) & 3;
      GLL16(Wg + (size_t)(n0 + row) * K + k0 + kb * 8, &Bs[b][idx * 8]);
    }
    if constexpr (TBN == 256) {
      int idx = 512 + tid;                  // units 512..1023
      int row = idx >> 2, pb = idx & 3;
      int kb = (pb - row - (row >> 2)) & 3;
      GLL16(Wg + (size_t)(n0 + row) * K + k0 + kb * 8, &Bs[b][idx * 8]);
    } else {                                // TBN == 192: units 512..767 by waves 0-3
      if (wid < 4) {
        int idx = 512 + tid;
        int row = idx >> 2, pb = idx & 3;
        int kb = (pb - row - (row >> 2)) & 3;
        GLL16(Wg + (size_t)(n0 + row) * K + k0 + kb * 8, &Bs[b][idx * 8]);
      }
    }
  };

  f32x4 acc[MA][NB] = {};
  int KT = K >> 5;

  // prologue: stage tiles 0,1,2
  stageA(0, 0);  stageB(0, 0);
  stageA(1, 32); stageB(1, 32);
  stageA(2, 64); stageB(2, 64);

  for (int t = 0; t < KT; t++) {
    // counted wait: tile t landed; tiles t+1, t+2 stay in flight
    if constexpr (TBN == 256) {
      if (t < KT - 2)       asm volatile("s_waitcnt vmcnt(%0)" :: "n"(2 * (LDA + 2)) : "memory");
      else if (t == KT - 2) asm volatile("s_waitcnt vmcnt(%0)" :: "n"(LDA + 2) : "memory");
      else                  asm volatile("s_waitcnt vmcnt(0)" ::: "memory");
    } else {
      if (t < KT - 2) {
        if (wid < 4) asm volatile("s_waitcnt vmcnt(%0)" :: "n"(2 * (LDA + 2)) : "memory");
        else         asm volatile("s_waitcnt vmcnt(%0)" :: "n"(2 * (LDA + 1)) : "memory");
      } else if (t == KT - 2) {
        if (wid < 4) asm volatile("s_waitcnt vmcnt(%0)" :: "n"(LDA + 2) : "memory");
        else         asm volatile("s_waitcnt vmcnt(%0)" :: "n"(LDA + 1) : "memory");
      } else {
        asm volatile("s_waitcnt vmcnt(0)" ::: "memory");
      }
    }
    __builtin_amdgcn_s_barrier();
    __builtin_amdgcn_sched_barrier(0);

    const u16* as = &As[t & 3][0];
    const u16* bs = &Bs[t & 3][0];
    bool st = (t + 3) < KT;
    int sb = (t + 3) & 3, sk = (t + 3) << 5;

    // ---- phase A: B-frags + first half of A rows; stage A-unit of t+3 ----
    bf16x8 bfr[NB], afA[MA / 2];
#pragma unroll
    for (int q = 0; q < NB; q++) {
      int row = wn * WNC + q * 16 + l15;
      bfr[q] = *(const bf16x8*)&bs[row * 32 + ((lhi + row + (row >> 2)) & 3) * 8];
    }
#pragma unroll
    for (int p = 0; p < MA / 2; p++) {
      int row = wm * (TBM / 2) + p * 16 + l15;
      afA[p] = *(const bf16x8*)&as[row * 32 + ((lhi + row + (row >> 2)) & 3) * 8];
    }
    if (st) stageA(sb, sk);
    __builtin_amdgcn_s_setprio(1);
#pragma unroll
    for (int p = 0; p < MA / 2; p++)
#pragma unroll
      for (int q = 0; q < NB; q++)
        acc[p][q] = __builtin_amdgcn_mfma_f32_16x16x32_bf16(afA[p], bfr[q], acc[p][q], 0, 0, 0);
    __builtin_amdgcn_s_setprio(0);

    // ---- phase B: second half of A rows; stage B-unit of t+3 ----
    bf16x8 afB[MA / 2];
#pragma unroll
    for (int p = 0; p < MA / 2; p++) {
      int row = wm * (TBM / 2) + (MA / 2) * 16 + p * 16 + l15;
      afB[p] = *(const bf16x8*)&as[row * 32 + ((lhi + row + (row >> 2)) & 3) * 8];
    }
    if (st) stageB(sb, sk);
    __builtin_amdgcn_s_setprio(1);
#pragma unroll
    for (int p = 0; p < MA / 2; p++)
#pragma unroll
      for (int q = 0; q < NB; q++)
        acc[MA / 2 + p][q] = __builtin_amdgcn_mfma_f32_16x16x32_bf16(afB[p], bfr[q], acc[MA / 2 + p][q], 0, 0, 0);
    __builtin_amdgcn_s_setprio(0);
  }

  // epilogue: per-column segment resolve (tile may cross the 4096 boundary in mode 3)
#pragma unroll
  for (int p = 0; p < MA; p++) {
    int m = m0 + wm * (TBM / 2) + p * 16 + lhi * 4;
#pragma unroll
    for (int q = 0; q < NB; q++) {
      int n = n0 + wn * WNC + q * 16 + l15;
      const float* bias; void* Cout; int mode_l, nl;
      if (mode == 3) {
        int seg = n >> 12; nl = n & 4095;
        bias = (seg == 0) ? b0 : (seg == 1) ? b1 : b2;
        Cout = (seg == 0) ? C0 : (seg == 1) ? C1 : C2;
        mode_l = (seg == 2) ? 2 : 0;
      } else { bias = b0; Cout = C0; mode_l = mode; nl = n; }
      float bs2 = bias[nl];
      if (mode_l == 2) {
        u16x4 pk;
#pragma unroll
        for (int r = 0; r < 4; r++) pk[r] = f2bf(acc[p][q][r] + bs2);
        *(u16x4*)&((u16*)Cout)[(size_t)nl * M + m] = pk;   // V^T
      } else if (mode_l == 1) {
#pragma unroll
        for (int r = 0; r < 4; r++)
          ((float*)Cout)[(size_t)(m + r) * EMB + nl] = acc[p][q][r] + bs2;
      } else {
#pragma unroll
        for (int r = 0; r < 4; r++)
          ((u16*)Cout)[(size_t)(m + r) * EMB + nl] = f2bf(acc[p][q][r] + bs2);
      }
    }
  }
}

// ---------------- Flash attention (causal), QB=128 (8 waves x 16 rows), KVB=64 ----------
constexpr int QB = 128, KVB = 64;

__global__ __launch_bounds__(512) void k_flash(
    const u16* __restrict__ Q, const u16* __restrict__ K, const u16* __restrict__ VT,
    u16* __restrict__ ctx)
{
  __shared__ alignas(16) u16 Ks[2][KVB * 128];
  __shared__ alignas(16) u16 Vt[2][HD * 64];
  __shared__ alignas(16) u16 Pl[8][16 * 64];

  int tid = threadIdx.x, lane = tid & 63, wid = tid >> 6;   // wid 0..7
  int l15 = lane & 15, lhi = lane >> 4;
  int h = blockIdx.y;

  auto stage = [&](int buf, int t2) {
    int kv = t2 * KVB;
#pragma unroll
    for (int it = 0; it < 2; it++) {
      int chunk = tid + it * 512;
      int r = chunk >> 4, bp = chunk & 15;
      GLL16(K + (size_t)(kv + r) * EMB + h * HD + (((bp - r) & 15) << 3), &Ks[buf][chunk * 8]);
    }
#pragma unroll
    for (int it = 0; it < 2; it++) {
      int chunk = tid + it * 512;
      int d = chunk >> 3, bp = chunk & 7;
      GLL16(VT + (size_t)(h * HD + d) * SEQ + kv + (((bp - d) & 7) << 3), &Vt[buf][chunk * 8]);
    }
  };

  for (int pi = 0; pi < 2; pi++) {
    int qb = pi ? (int)blockIdx.x : 15 - (int)blockIdx.x;   // heavy first
    int q0 = qb * QB;
    int qw = q0 + wid * 16;

    bf16x8 qf[4];
#pragma unroll
    for (int kc = 0; kc < 4; kc++)
      qf[kc] = *(const bf16x8*)&Q[(size_t)(qw + l15) * EMB + h * HD + kc * 32 + lhi * 8];

    f32x4 O[8] = {};
    float mrow[4], lrow[4];
#pragma unroll
    for (int r = 0; r < 4; r++) { mrow[r] = -3.0e38f; lrow[r] = 0.f; }

    int nt = 2 * (qb + 1);
    __syncthreads();
    stage(0, 0);
    for (int t = 0; t < nt; t++) {
      __syncthreads();
      if (t + 1 < nt) stage((t + 1) & 1, t + 1);

      int kv0 = t * KVB;
      if (kv0 > qw + 15) continue;   // fully masked for this wave

      const u16* ks = Ks[t & 1];
      const u16* vt = Vt[t & 1];
      float p[4][4];
      bool need_mask = (kv0 + KVB - 1) > qw;
#pragma unroll
      for (int c = 0; c < 4; c++) {
        f32x4 s = {};
        int r0 = c * 16 + l15;
#pragma unroll
        for (int kc = 0; kc < 4; kc++) {
          bf16x8 kf = *(const bf16x8*)&ks[r0 * 128 + (((kc * 4 + lhi) + r0) & 15) * 8];
          s = __builtin_amdgcn_mfma_f32_16x16x32_bf16(qf[kc], kf, s, 0, 0, 0);
        }
#pragma unroll
        for (int r = 0; r < 4; r++) {
          float sv = s[r];
          if (need_mask) {
            int qg = qw + lhi * 4 + r;
            int kg = kv0 + c * 16 + l15;
            if (kg > qg) sv = -3.0e38f;
          }
          p[c][r] = sv;
        }
      }
      float fscale[4];
#pragma unroll
      for (int r = 0; r < 4; r++) {
        float m = fmaxf(fmaxf(p[0][r], p[1][r]), fmaxf(p[2][r], p[3][r]));
#pragma unroll
        for (int x = 1; x < 16; x <<= 1) m = fmaxf(m, __shfl_xor(m, x, 64));
        float mnew = fmaxf(mrow[r], m);
        fscale[r] = __expf(mrow[r] - mnew);
        mrow[r] = mnew;
      }
#pragma unroll
      for (int c = 0; c < 4; c++)
#pragma unroll
        for (int r = 0; r < 4; r++)
          p[c][r] = __expf(p[c][r] - mrow[r]);
#pragma unroll
      for (int r = 0; r < 4; r++) {
        float s = p[0][r] + p[1][r] + p[2][r] + p[3][r];
#pragma unroll
        for (int x = 1; x < 16; x <<= 1) s += __shfl_xor(s, x, 64);
        lrow[r] = lrow[r] * fscale[r] + s;
      }
#pragma unroll
      for (int d = 0; d < 8; d++)
#pragma unroll
        for (int r = 0; r < 4; r++)
          O[d][r] *= fscale[r];
#pragma unroll
      for (int c = 0; c < 4; c++) {
        int kb = c * 2 + (l15 >> 3), klo = l15 & 7;
#pragma unroll
        for (int r = 0; r < 4; r++) {
          int q = lhi * 4 + r;
          Pl[wid][q * 64 + ((kb + (q >> 1)) & 7) * 8 + klo] = f2bf(p[c][r]);
        }
      }
#pragma unroll
      for (int ks2 = 0; ks2 < 2; ks2++) {
        int kb = ks2 * 4 + lhi;
        bf16x8 pf = *(const bf16x8*)&Pl[wid][l15 * 64 + ((kb + (l15 >> 1)) & 7) * 8];
#pragma unroll
        for (int ds = 0; ds < 8; ds++) {
          int d = ds * 16 + l15;
          bf16x8 vf = *(const bf16x8*)&vt[d * 64 + ((kb + d) & 7) * 8];
          O[ds] = __builtin_amdgcn_mfma_f32_16x16x32_bf16(pf, vf, O[ds], 0, 0, 0);
        }
      }
    }

#pragma unroll
    for (int r = 0; r < 4; r++) {
      float inv = 1.f / lrow[r];
      int qg = q0 + wid * 16 + lhi * 4 + r;
#pragma unroll
      for (int ds = 0; ds < 8; ds++)
        ctx[(size_t)qg * EMB + h * HD + ds * 16 + l15] = f2bf(O[ds][r] * inv);
    }
  }
}

// ---------------- launch ----------------
extern "C" void kernel_launch(void* const* d_in, const int* in_sizes, int n_in,
                              void* d_out, int out_size, void* d_ws, size_t ws_size,
                              hipStream_t stream) {
  const float* hs = (const float*)d_in[0];
  const float* wq = (const float*)d_in[1];
  const float* bq = (const float*)d_in[2];
  const float* wk = (const float*)d_in[3];
  const float* bk = (const float*)d_in[4];
  const float* wv = (const float*)d_in[5];
  const float* bv = (const float*)d_in[6];
  const float* wo = (const float*)d_in[7];
  const float* bo = (const float*)d_in[8];
  const int*  pos = (const int*)d_in[9];

  const size_t SE = (size_t)SEQ * EMB;   // 8M elems
  const size_t EE = (size_t)EMB * EMB;   // 16M elems = 2^24
  const float qscale = 1.0f / 11.313708498984761f;  // 1/sqrt(128)

  char* ws = (char*)d_ws;
  size_t off = 0;
  auto alloc = [&](size_t b) { size_t o = off; off += (b + 255) & ~(size_t)255; return o; };

  size_t need_fused = ((SE * 2 + 255) & ~255ULL) + ((EE * 6 + 255) & ~255ULL) +
                      3 * ((SE * 2 + 255) & ~255ULL) + ((size_t)SEQ * HALF * 8 + 255);
  bool fused = ws_size >= need_fused + 4096;

  u16*  hsb = (u16*)(ws + alloc(SE * 2));
  u16*  wb  = (u16*)(ws + alloc(fused ? EE * 6 : EE * 2));  // fused: wq|wk|wv, reused for wo
  u16*  Qb  = (u16*)(ws + alloc(SE * 2));
  u16*  Kb  = (u16*)(ws + alloc(SE * 2));
  u16*  VTb = (u16*)(ws + alloc(SE * 2));                   // V^T, [E][S]
  float* tab = (float*)(ws + alloc((size_t)SEQ * HALF * 2 * 4));
  u16*  ctxb = hsb;   // hs dead after QKV GEMM; flash output reuses it

  dim3 cb(256);
  k_f32_to_bf16<<<dim3(SE / 2048), cb, 0, stream>>>(hs, hsb, (int)SE);
  k_rope_table<<<dim3(SEQ * HALF / 256), cb, 0, stream>>>(pos, tab);

  if (fused) {
    k_w3_to_bf16<<<dim3(3 * EE / 2048), cb, 0, stream>>>(wq, wk, wv, wb);
    // fused QKV GEMM: 256x192 tile -> grid 8x64 = 512 = 2 EXACT rounds of 256 CUs
    k_qkv4<256, 192><<<dim3(512), dim3(512), 0, stream>>>(
        hsb, wb, bq, bk, bv, (void*)Qb, (void*)Kb, (void*)VTb, SEQ, 3 * EMB, EMB, 3);
  } else {
    k_f32_to_bf16<<<dim3(EE / 2048), cb, 0, stream>>>(wq, wb, (int)EE);
    k_qkv4<256, 256><<<dim3(128), dim3(512), 0, stream>>>(
        hsb, wb, bq, bq, bq, (void*)Qb, nullptr, nullptr, SEQ, EMB, EMB, 0);
    k_f32_to_bf16<<<dim3(EE / 2048), cb, 0, stream>>>(wk, wb, (int)EE);
    k_qkv4<256, 256><<<dim3(128), dim3(512), 0, stream>>>(
        hsb, wb, bk, bk, bk, (void*)Kb, nullptr, nullptr, SEQ, EMB, EMB, 0);
    k_f32_to_bf16<<<dim3(EE / 2048), cb, 0, stream>>>(wv, wb, (int)EE);
    k_qkv4<256, 256><<<dim3(128), dim3(512), 0, stream>>>(
        hsb, wb, bv, bv, bv, (void*)VTb, nullptr, nullptr, SEQ, EMB, EMB, 2);
  }

  k_rope<<<dim3(SEQ * NH * HALF / 256), cb, 0, stream>>>(Qb, tab, qscale);
  k_rope<<<dim3(SEQ * NH * HALF / 256), cb, 0, stream>>>(Kb, tab, 1.0f);

  // attention: QB=128, grid 8x32 = 256 blocks (1 exact round)
  k_flash<<<dim3(8, NH), dim3(512), 0, stream>>>(Qb, Kb, VTb, ctxb);

  // output projection: 128x256 tile -> grid 256 (1 exact round), f32 out
  k_f32_to_bf16<<<dim3(EE / 2048), cb, 0, stream>>>(wo, wb, (int)EE);
  k_qkv4<128, 256><<<dim3(256), dim3(512), 0, stream>>>(
      ctxb, wb, bo, bo, bo, d_out, nullptr, nullptr, SEQ, EMB, EMB, 1);
}